// Round 1
// baseline (110.118 us; speedup 1.0000x reference)
//
#include <hip/hip_runtime.h>

#define BB 1024
#define QQ 128
#define TT 32
#define NC 257
#define FINF 1e9f

// ---------------- Kernel 1: cost matrix ----------------
// One wave per (b,q) row. 64 lanes reduce softmax over 257 classes, then
// lanes 0..31 each emit C[b,q,t] for one t.
__global__ __launch_bounds__(256) void cost_kernel(
    const float* __restrict__ logits,
    const float4* __restrict__ pboxes,
    const int* __restrict__ tlabels,
    const float4* __restrict__ tboxes,
    float* __restrict__ Cmat)
{
    const int wave = threadIdx.x >> 6;
    const int lane = threadIdx.x & 63;
    const int r = blockIdx.x * 4 + wave;      // r = b*Q + q
    const int b = r >> 7;
    const float* lrow = logits + (size_t)r * NC;

    float x0 = lrow[lane];
    float x1 = lrow[lane + 64];
    float x2 = lrow[lane + 128];
    float x3 = lrow[lane + 192];
    float m = fmaxf(fmaxf(x0, x1), fmaxf(x2, x3));
    float x4 = 0.f;
    if (lane == 0) { x4 = lrow[256]; m = fmaxf(m, x4); }
    for (int o = 1; o < 64; o <<= 1) m = fmaxf(m, __shfl_xor(m, o));
    float s = expf(x0 - m) + expf(x1 - m) + expf(x2 - m) + expf(x3 - m);
    if (lane == 0) s += expf(x4 - m);
    for (int o = 1; o < 64; o <<= 1) s += __shfl_xor(s, o);

    float4 pb = pboxes[r];
    float px0 = pb.x - 0.5f * pb.z, py0 = pb.y - 0.5f * pb.w;
    float px1 = pb.x + 0.5f * pb.z, py1 = pb.y + 0.5f * pb.w;
    float parea = (px1 - px0) * (py1 - py0);

    if (lane < TT) {
        int t = lane;
        int lbl = tlabels[b * TT + t];
        float cls = -(expf(lrow[lbl] - m) / s);
        float4 tb = tboxes[b * TT + t];
        float cb = fabsf(pb.x - tb.x) + fabsf(pb.y - tb.y)
                 + fabsf(pb.z - tb.z) + fabsf(pb.w - tb.w);
        float tx0 = tb.x - 0.5f * tb.z, ty0 = tb.y - 0.5f * tb.w;
        float tx1 = tb.x + 0.5f * tb.z, ty1 = tb.y + 0.5f * tb.w;
        float tarea = (tx1 - tx0) * (ty1 - ty0);
        float iw = fmaxf(fminf(px1, tx1) - fmaxf(px0, tx0), 0.f);
        float ih = fmaxf(fminf(py1, ty1) - fmaxf(py0, ty0), 0.f);
        float inter = iw * ih;
        float uni = parea + tarea - inter;
        float iou = inter / uni;
        float cw = fmaxf(fmaxf(px1, tx1) - fminf(px0, tx0), 0.f);
        float ch = fmaxf(fmaxf(py1, ty1) - fminf(py0, ty0), 0.f);
        float ca = cw * ch;
        float giou = iou - (ca - uni) / (ca + 1e-6f);
        Cmat[(size_t)r * TT + t] = 5.0f * cb + cls - 2.0f * giou;
    }
}

// ---------------- Kernel 2: rectangular Jonker-Volgenant LSA ----------------
// One 64-lane wave per batch. Solve the TRANSPOSED rectangular problem:
// 32 rows (targets t), 128 cols (queries q). Equivalent to the reference's
// 0-padded square (its own comment: "== rectangular LSA"), but 4x fewer phases.
// Each lane owns 2 columns (lane, lane+64): v/minv/used in registers.
// u[32], p[128] (row assigned to col, -1 free), way[128] in LDS.
__global__ __launch_bounds__(64) void lsa_kernel(
    const float* __restrict__ Cmat,
    float* __restrict__ rows_out,
    float* __restrict__ cols_out)
{
    const int b = blockIdx.x;
    const int lane = threadIdx.x;

    __shared__ float a[TT][QQ + 1];   // a[t][q], +1 pad: conflict-free staging
    __shared__ float u_lds[TT];
    __shared__ int p_lds[QQ];
    __shared__ int way_lds[QQ];
    __shared__ int x4row[TT];

    const float* Cb = Cmat + (size_t)b * QQ * TT;
    for (int e = lane; e < QQ * TT; e += 64) {
        a[e & 31][e >> 5] = Cb[e];    // e = q*32 + t  ->  a[t][q]
    }
    if (lane < TT) u_lds[lane] = 0.f;
    p_lds[lane] = -1;
    p_lds[lane + 64] = -1;
    __syncthreads();

    float v0 = 0.f, v1 = 0.f;         // column potentials (2 cols per lane)

    for (int i = 0; i < TT; ++i) {
        float minv0 = FINF, minv1 = FINF;
        bool used0 = false, used1 = false;
        int j0 = -1;                  // -1 == virtual column, p[virtual] = i
        while (true) {
            int i0;
            if (j0 >= 0) {
                if (j0 < 64) { if (lane == j0) used0 = true; }
                else         { if (lane == j0 - 64) used1 = true; }
                i0 = p_lds[j0];
            } else {
                i0 = i;
            }
            float ui0 = u_lds[i0];
            float c0 = a[i0][lane] - ui0 - v0;
            float c1 = a[i0][lane + 64] - ui0 - v1;
            if (!used0 && c0 < minv0) { minv0 = c0; way_lds[lane] = j0; }
            if (!used1 && c1 < minv1) { minv1 = c1; way_lds[lane + 64] = j0; }
            float m0 = used0 ? FINF : minv0;
            float m1 = used1 ? FINF : minv1;
            float mv; int mj;
            if (m1 < m0) { mv = m1; mj = lane + 64; } else { mv = m0; mj = lane; }
            for (int o = 1; o < 64; o <<= 1) {
                float ov = __shfl_xor(mv, o);
                int   oj = __shfl_xor(mj, o);
                if (ov < mv || (ov == mv && oj < mj)) { mv = ov; mj = oj; }
            }
            const float delta = mv;
            const int j1 = mj;
            // dual updates: used cols shift potentials, unused cols shrink minv
            if (used0) { v0 -= delta; u_lds[p_lds[lane]] += delta; }
            else       { minv0 -= delta; }
            if (used1) { v1 -= delta; u_lds[p_lds[lane + 64]] += delta; }
            else       { minv1 -= delta; }
            if (lane == 0) u_lds[i] += delta;   // virtual col is always used
            __syncthreads();
            j0 = j1;
            if (p_lds[j1] < 0) break;           // reached a free column
        }
        // augment along way[] back to the virtual column
        if (lane == 0) {
            int j = j0;
            while (true) {
                int jprev = way_lds[j];
                p_lds[j] = (jprev < 0) ? i : p_lds[jprev];
                if (jprev < 0) break;
                j = jprev;
            }
        }
        __syncthreads();
    }

    // invert p (col->row) to row->col, then rank-sort by assigned q ascending
    if (p_lds[lane] >= 0)      x4row[p_lds[lane]] = lane;
    if (p_lds[lane + 64] >= 0) x4row[p_lds[lane + 64]] = lane + 64;
    __syncthreads();
    if (lane < TT) {
        int val = x4row[lane];          // q assigned to target 'lane'
        int rank = 0;
        for (int t2 = 0; t2 < TT; ++t2) {
            int other = __shfl(val, t2);
            rank += (other < val) ? 1 : 0;
        }
        rows_out[b * TT + rank] = (float)val;
        cols_out[b * TT + rank] = (float)lane;
    }
}

extern "C" void kernel_launch(void* const* d_in, const int* in_sizes, int n_in,
                              void* d_out, int out_size, void* d_ws, size_t ws_size,
                              hipStream_t stream)
{
    const float*  logits  = (const float*)d_in[0];
    const float4* pboxes  = (const float4*)d_in[1];
    const int*    tlabels = (const int*)d_in[2];
    const float4* tboxes  = (const float4*)d_in[3];
    float* out  = (float*)d_out;
    float* Cmat = out;                                   // [B,Q,T] float
    float* rows = out + (size_t)BB * QQ * TT;            // [B,T] as float
    float* cols = rows + (size_t)BB * TT;                // [B,T] as float
    cost_kernel<<<(BB * QQ) / 4, 256, 0, stream>>>(logits, pboxes, tlabels, tboxes, Cmat);
    lsa_kernel<<<BB, 64, 0, stream>>>(Cmat, rows, cols);
}

// Round 2
// 90.157 us; speedup vs baseline: 1.2214x; 1.2214x over previous
//
#include <hip/hip_runtime.h>

#define BB 1024
#define QQ 128
#define TT 32
#define NC 257
#define FINF 1e9f

// ---------------- Kernel 1: cost matrix ----------------
// One wave per (b,q) row. 64 lanes reduce softmax over 257 classes, then
// lanes 0..31 each emit C[b,q,t] for one t.
__global__ __launch_bounds__(256) void cost_kernel(
    const float* __restrict__ logits,
    const float4* __restrict__ pboxes,
    const int* __restrict__ tlabels,
    const float4* __restrict__ tboxes,
    float* __restrict__ Cmat)
{
    const int wave = threadIdx.x >> 6;
    const int lane = threadIdx.x & 63;
    const int r = blockIdx.x * 4 + wave;      // r = b*Q + q
    const int b = r >> 7;
    const float* lrow = logits + (size_t)r * NC;

    float x0 = lrow[lane];
    float x1 = lrow[lane + 64];
    float x2 = lrow[lane + 128];
    float x3 = lrow[lane + 192];
    float m = fmaxf(fmaxf(x0, x1), fmaxf(x2, x3));
    float x4 = 0.f;
    if (lane == 0) { x4 = lrow[256]; m = fmaxf(m, x4); }
    for (int o = 1; o < 64; o <<= 1) m = fmaxf(m, __shfl_xor(m, o));
    float s = expf(x0 - m) + expf(x1 - m) + expf(x2 - m) + expf(x3 - m);
    if (lane == 0) s += expf(x4 - m);
    for (int o = 1; o < 64; o <<= 1) s += __shfl_xor(s, o);

    float4 pb = pboxes[r];
    float px0 = pb.x - 0.5f * pb.z, py0 = pb.y - 0.5f * pb.w;
    float px1 = pb.x + 0.5f * pb.z, py1 = pb.y + 0.5f * pb.w;
    float parea = (px1 - px0) * (py1 - py0);

    if (lane < TT) {
        int t = lane;
        int lbl = tlabels[b * TT + t];
        float cls = -(expf(lrow[lbl] - m) / s);
        float4 tb = tboxes[b * TT + t];
        float cb = fabsf(pb.x - tb.x) + fabsf(pb.y - tb.y)
                 + fabsf(pb.z - tb.z) + fabsf(pb.w - tb.w);
        float tx0 = tb.x - 0.5f * tb.z, ty0 = tb.y - 0.5f * tb.w;
        float tx1 = tb.x + 0.5f * tb.z, ty1 = tb.y + 0.5f * tb.w;
        float tarea = (tx1 - tx0) * (ty1 - ty0);
        float iw = fmaxf(fminf(px1, tx1) - fmaxf(px0, tx0), 0.f);
        float ih = fmaxf(fminf(py1, ty1) - fmaxf(py0, ty0), 0.f);
        float inter = iw * ih;
        float uni = parea + tarea - inter;
        float iou = inter / uni;
        float cw = fmaxf(fmaxf(px1, tx1) - fminf(px0, tx0), 0.f);
        float ch = fmaxf(fmaxf(py1, ty1) - fminf(py0, ty0), 0.f);
        float ca = cw * ch;
        float giou = iou - (ca - uni) / (ca + 1e-6f);
        Cmat[(size_t)r * TT + t] = 5.0f * cb + cls - 2.0f * giou;
    }
}

// ---------------- Kernel 2: rectangular Jonker-Volgenant LSA ----------------
// One 64-lane wave per batch, transposed problem: 32 rows (targets), 128 cols
// (queries). ALL mutable state in registers:
//   lane owns columns q=2*lane, 2*lane+1  -> v0/v1, minv0/minv1, used0/used1,
//   way0/way1, p0/p1 (assigned row, -1 free).
//   lanes 0..31 own rows -> u (potential), in_tree flag.
// JV's "u[p[j]] += delta for used j, u[i] += delta" == "u += delta for rows in
// the alternating tree" == lane-local predicated add. No LDS writes, no
// __syncthreads in the main loop. LDS holds only the read-only cost tile,
// stride QQ+2=130 floats: stage writes and ds_read_b64 both 2-way (free).
__global__ __launch_bounds__(64) void lsa_kernel(
    const float* __restrict__ Cmat,
    float* __restrict__ rows_out,
    float* __restrict__ cols_out)
{
    const int b = blockIdx.x;
    const int lane = threadIdx.x;

    __shared__ float a[TT][QQ + 2];   // a[t][q]
    __shared__ int x4row[TT];

    // stage transposed, float4 global loads (e = q*32 + t)
    const float4* Cb4 = (const float4*)(Cmat + (size_t)b * QQ * TT);
    #pragma unroll
    for (int k = 0; k < 16; ++k) {
        int idx = k * 64 + lane;
        float4 c4 = Cb4[idx];
        int q = idx >> 3;
        int t0 = (idx & 7) * 4;
        a[t0 + 0][q] = c4.x;
        a[t0 + 1][q] = c4.y;
        a[t0 + 2][q] = c4.z;
        a[t0 + 3][q] = c4.w;
    }
    __syncthreads();

    float v0 = 0.f, v1 = 0.f;
    int p0 = -1, p1 = -1;
    float u = 0.f;                    // row potential (meaningful on lanes<32)

    for (int i = 0; i < TT; ++i) {
        float minv0 = FINF, minv1 = FINF;
        int way0 = -1, way1 = -1;     // -1 == came from virtual root
        bool used0 = false, used1 = false;
        bool in_tree = (lane == i);
        int i0 = i;                   // row being scanned (uniform)
        int jcur = -1;                // column we arrived from
        int jfree;

        while (true) {
            float ui0 = __shfl(u, i0);
            const float2 arow = *(const float2*)&a[i0][2 * lane];
            float c0 = arow.x - ui0 - v0;
            float c1 = arow.y - ui0 - v1;
            if (!used0 && c0 < minv0) { minv0 = c0; way0 = jcur; }
            if (!used1 && c1 < minv1) { minv1 = c1; way1 = jcur; }
            float m0 = used0 ? FINF : minv0;
            float m1 = used1 ? FINF : minv1;
            float lv; int lj;
            if (m1 < m0) { lv = m1; lj = 2 * lane + 1; }
            else         { lv = m0; lj = 2 * lane; }
            float g = lv;
            for (int o = 1; o < 64; o <<= 1) g = fminf(g, __shfl_xor(g, o));
            const float delta = g;
            unsigned long long mask = __ballot(lv == g);
            int src = __ffsll((unsigned long long)mask) - 1;
            int j1 = __shfl(lj, src);
            // dual updates (before examining j1, matching reference order)
            if (used0) v0 -= delta; else minv0 -= delta;
            if (used1) v1 -= delta; else minv1 -= delta;
            if (in_tree) u += delta;
            // examine column j1
            int pj1 = __shfl((j1 & 1) ? p1 : p0, j1 >> 1);
            if (pj1 < 0) { jfree = j1; break; }
            if (lane == (j1 >> 1)) { if (j1 & 1) used1 = true; else used0 = true; }
            if (lane == pj1) in_tree = true;
            i0 = pj1;
            jcur = j1;
        }

        // augment: walk way[] back to the virtual root (all lanes, shuffles)
        int j = jfree;
        while (true) {
            int jprev = __shfl((j & 1) ? way1 : way0, j >> 1);
            int pnew = (jprev < 0) ? i
                     : __shfl((jprev & 1) ? p1 : p0, jprev >> 1);
            if (lane == (j >> 1)) { if (j & 1) p1 = pnew; else p0 = pnew; }
            if (jprev < 0) break;
            j = jprev;
        }
    }

    // invert col->row to row->col, then rank-sort by assigned q ascending
    if (p0 >= 0) x4row[p0] = 2 * lane;
    if (p1 >= 0) x4row[p1] = 2 * lane + 1;
    __syncthreads();
    if (lane < TT) {
        int val = x4row[lane];        // q assigned to target 'lane'
        int rank = 0;
        for (int t2 = 0; t2 < TT; ++t2) {
            int other = __shfl(val, t2);
            rank += (other < val) ? 1 : 0;
        }
        rows_out[b * TT + rank] = (float)val;
        cols_out[b * TT + rank] = (float)lane;
    }
}

extern "C" void kernel_launch(void* const* d_in, const int* in_sizes, int n_in,
                              void* d_out, int out_size, void* d_ws, size_t ws_size,
                              hipStream_t stream)
{
    const float*  logits  = (const float*)d_in[0];
    const float4* pboxes  = (const float4*)d_in[1];
    const int*    tlabels = (const int*)d_in[2];
    const float4* tboxes  = (const float4*)d_in[3];
    float* out  = (float*)d_out;
    float* Cmat = out;                                   // [B,Q,T] float
    float* rows = out + (size_t)BB * QQ * TT;            // [B,T] as float
    float* cols = rows + (size_t)BB * TT;                // [B,T] as float
    cost_kernel<<<(BB * QQ) / 4, 256, 0, stream>>>(logits, pboxes, tlabels, tboxes, Cmat);
    lsa_kernel<<<BB, 64, 0, stream>>>(Cmat, rows, cols);
}

// Round 3
// 69.511 us; speedup vs baseline: 1.5842x; 1.2970x over previous
//
#include <hip/hip_runtime.h>

#define BB 1024
#define QQ 128
#define TT 32
#define NC 257
#define FINF 1e9f

// ---------- fast cross-lane helpers (DPP + readlane; no ds_swizzle) ----------
__device__ __forceinline__ int rl_i(int v, int l) {
    return __builtin_amdgcn_readlane(v, l);
}
__device__ __forceinline__ float rl_f(float v, int l) {
    return __int_as_float(__builtin_amdgcn_readlane(__float_as_int(v), l));
}
#define DPP_STEP_MIN(x, ctrl) \
    x = fminf(x, __int_as_float(__builtin_amdgcn_update_dpp( \
        __float_as_int(x), __float_as_int(x), ctrl, 0xf, 0xf, false)))
#define DPP_STEP_MAX(x, ctrl) \
    x = fmaxf(x, __int_as_float(__builtin_amdgcn_update_dpp( \
        __float_as_int(x), __float_as_int(x), ctrl, 0xf, 0xf, false)))
#define DPP_STEP_ADD(x, ctrl) \
    x = x + __int_as_float(__builtin_amdgcn_update_dpp( \
        0, __float_as_int(x), ctrl, 0xf, 0xf, false))

// full-wave min, result returned as wave-uniform scalar (SGPR)
__device__ __forceinline__ float wave_min64(float x) {
    DPP_STEP_MIN(x, 0xB1);   // quad_perm [1,0,3,2]  (xor 1)
    DPP_STEP_MIN(x, 0x4E);   // quad_perm [2,3,0,1]  (xor 2)
    DPP_STEP_MIN(x, 0x141);  // row_half_mirror      (8-group)
    DPP_STEP_MIN(x, 0x140);  // row_mirror           (16-group)
    DPP_STEP_MIN(x, 0x142);  // row_bcast15
    DPP_STEP_MIN(x, 0x143);  // row_bcast31 -> lane 63 has global min
    return rl_f(x, 63);
}
__device__ __forceinline__ float wave_max64(float x) {
    DPP_STEP_MAX(x, 0xB1); DPP_STEP_MAX(x, 0x4E);
    DPP_STEP_MAX(x, 0x141); DPP_STEP_MAX(x, 0x140);
    DPP_STEP_MAX(x, 0x142); DPP_STEP_MAX(x, 0x143);
    return rl_f(x, 63);
}
__device__ __forceinline__ float wave_add64(float x) {
    DPP_STEP_ADD(x, 0xB1); DPP_STEP_ADD(x, 0x4E);
    DPP_STEP_ADD(x, 0x141); DPP_STEP_ADD(x, 0x140);
    DPP_STEP_ADD(x, 0x142); DPP_STEP_ADD(x, 0x143);
    return rl_f(x, 63);
}

// ---------------- Kernel 1: cost matrix ----------------
__global__ __launch_bounds__(256) void cost_kernel(
    const float* __restrict__ logits,
    const float4* __restrict__ pboxes,
    const int* __restrict__ tlabels,
    const float4* __restrict__ tboxes,
    float* __restrict__ Cmat)
{
    const int wave = threadIdx.x >> 6;
    const int lane = threadIdx.x & 63;
    const int r = blockIdx.x * 4 + wave;      // r = b*Q + q
    const int b = r >> 7;
    const float* lrow = logits + (size_t)r * NC;

    float x0 = lrow[lane];
    float x1 = lrow[lane + 64];
    float x2 = lrow[lane + 128];
    float x3 = lrow[lane + 192];
    float mloc = fmaxf(fmaxf(x0, x1), fmaxf(x2, x3));
    float x4 = 0.f;
    if (lane == 0) { x4 = lrow[256]; mloc = fmaxf(mloc, x4); }
    float m = wave_max64(mloc);
    float sloc = expf(x0 - m) + expf(x1 - m) + expf(x2 - m) + expf(x3 - m);
    if (lane == 0) sloc += expf(x4 - m);
    float s = wave_add64(sloc);

    float4 pb = pboxes[r];
    float px0 = pb.x - 0.5f * pb.z, py0 = pb.y - 0.5f * pb.w;
    float px1 = pb.x + 0.5f * pb.z, py1 = pb.y + 0.5f * pb.w;
    float parea = (px1 - px0) * (py1 - py0);

    if (lane < TT) {
        int t = lane;
        int lbl = tlabels[b * TT + t];
        float cls = -(expf(lrow[lbl] - m) / s);
        float4 tb = tboxes[b * TT + t];
        float cb = fabsf(pb.x - tb.x) + fabsf(pb.y - tb.y)
                 + fabsf(pb.z - tb.z) + fabsf(pb.w - tb.w);
        float tx0 = tb.x - 0.5f * tb.z, ty0 = tb.y - 0.5f * tb.w;
        float tx1 = tb.x + 0.5f * tb.z, ty1 = tb.y + 0.5f * tb.w;
        float tarea = (tx1 - tx0) * (ty1 - ty0);
        float iw = fmaxf(fminf(px1, tx1) - fmaxf(px0, tx0), 0.f);
        float ih = fmaxf(fminf(py1, ty1) - fmaxf(py0, ty0), 0.f);
        float inter = iw * ih;
        float uni = parea + tarea - inter;
        float iou = inter / uni;
        float cw = fmaxf(fmaxf(px1, tx1) - fminf(px0, tx0), 0.f);
        float ch = fmaxf(fmaxf(py1, ty1) - fminf(py0, ty0), 0.f);
        float ca = cw * ch;
        float giou = iou - (ca - uni) / (ca + 1e-6f);
        Cmat[(size_t)r * TT + t] = 5.0f * cb + cls - 2.0f * giou;
    }
}

// ---------------- Kernel 2: JV LSA with row-reduction init ----------------
// One 64-lane wave per batch, transposed: 32 rows (targets) x 128 cols
// (queries). Lane owns cols {2l, 2l+1}; lanes 0..31 own row duals u.
// Init: u[t] = min_j a[t][j], v = 0 (feasible), greedy-assign tight edges
// (~27/32 rows). Dijkstra phases only for leftover rows. All cross-lane
// traffic via DPP reductions / ballot / readlane — no ds_swizzle/bpermute.
__global__ __launch_bounds__(64) void lsa_kernel(
    const float* __restrict__ Cmat,
    float* __restrict__ rows_out,
    float* __restrict__ cols_out)
{
    const int b = blockIdx.x;
    const int lane = threadIdx.x;

    __shared__ float a[TT][QQ + 2];   // a[t][q], stride 130 (2-way, free)
    __shared__ int x4row[TT];

    const float4* Cb4 = (const float4*)(Cmat + (size_t)b * QQ * TT);
    #pragma unroll
    for (int k = 0; k < 16; ++k) {
        int idx = k * 64 + lane;
        float4 c4 = Cb4[idx];         // idx = q*8 + t/4
        int q = idx >> 3;
        int t0 = (idx & 7) * 4;
        a[t0 + 0][q] = c4.x;
        a[t0 + 1][q] = c4.y;
        a[t0 + 2][q] = c4.z;
        a[t0 + 3][q] = c4.w;
    }
    __syncthreads();

    float v0 = 0.f, v1 = 0.f;
    int p0 = -1, p1 = -1;             // row assigned to col 2l / 2l+1
    float u = 0.f;                    // row potential (lanes 0..31)
    bool rowfree = (lane < TT);       // lane i<32: row i unassigned

    // ---- row reduction + greedy tight-edge assignment ----
    for (int i = 0; i < TT; ++i) {
        const float2 ar = *(const float2*)&a[i][2 * lane];
        float um = wave_min64(fminf(ar.x, ar.y));
        if (lane == i) u = um;
        bool cand0 = (ar.x == um) && (p0 < 0);
        bool cand1 = (ar.y == um) && (p1 < 0);
        unsigned long long m0 = __ballot(cand0);
        unsigned long long mm = m0 | __ballot(cand1);
        if (mm) {
            int s = __ffsll(mm) - 1;
            bool pick0 = (m0 >> s) & 1;
            if (lane == s) { if (pick0) p0 = i; else p1 = i; }
            if (lane == i) rowfree = false;
        }
    }

    // ---- Dijkstra augmentation for remaining free rows ----
    unsigned long long freerows = __ballot(rowfree);
    while (freerows) {
        const int i = __ffsll(freerows) - 1;
        freerows &= freerows - 1;

        float minv0 = FINF, minv1 = FINF;
        int way0 = -1, way1 = -1;
        bool used0 = false, used1 = false;
        bool in_tree = (lane == i);
        int i0 = i;
        int jcur = -1;
        int jfree;

        while (true) {
            float ui0 = rl_f(u, i0);
            const float2 ar = *(const float2*)&a[i0][2 * lane];
            float c0 = ar.x - ui0 - v0;
            float c1 = ar.y - ui0 - v1;
            if (!used0 && c0 < minv0) { minv0 = c0; way0 = jcur; }
            if (!used1 && c1 < minv1) { minv1 = c1; way1 = jcur; }
            float m0 = used0 ? FINF : minv0;
            float m1 = used1 ? FINF : minv1;
            float lv = fminf(m0, m1);
            const float delta = wave_min64(lv);
            unsigned long long eq = __ballot(lv == delta);
            int s = __ffsll(eq) - 1;
            unsigned long long which0 = __ballot(m0 <= m1);
            int j1 = 2 * s + (((which0 >> s) & 1) ? 0 : 1);
            // dual updates
            if (used0) v0 -= delta; else minv0 -= delta;
            if (used1) v1 -= delta; else minv1 -= delta;
            if (in_tree) u += delta;
            // examine column j1
            int pj1 = rl_i((j1 & 1) ? p1 : p0, j1 >> 1);
            if (pj1 < 0) { jfree = j1; break; }
            if (lane == (j1 >> 1)) { if (j1 & 1) used1 = true; else used0 = true; }
            if (lane == pj1) in_tree = true;
            i0 = pj1;
            jcur = j1;
        }

        // augment back to the root (scalar readlane walk)
        int j = jfree;
        while (true) {
            int jprev = rl_i((j & 1) ? way1 : way0, j >> 1);
            int pnew = (jprev < 0) ? i : rl_i((jprev & 1) ? p1 : p0, jprev >> 1);
            if (lane == (j >> 1)) { if (j & 1) p1 = pnew; else p0 = pnew; }
            if (jprev < 0) break;
            j = jprev;
        }
    }

    // invert col->row to row->col, then rank-sort by assigned q ascending
    if (p0 >= 0) x4row[p0] = 2 * lane;
    if (p1 >= 0) x4row[p1] = 2 * lane + 1;
    __syncthreads();
    if (lane < TT) {
        int val = x4row[lane];        // q assigned to target 'lane'
        int rank = 0;
        for (int t2 = 0; t2 < TT; ++t2) {
            int other = rl_i(val, t2);
            rank += (other < val) ? 1 : 0;
        }
        rows_out[b * TT + rank] = (float)val;
        cols_out[b * TT + rank] = (float)lane;
    }
}

extern "C" void kernel_launch(void* const* d_in, const int* in_sizes, int n_in,
                              void* d_out, int out_size, void* d_ws, size_t ws_size,
                              hipStream_t stream)
{
    const float*  logits  = (const float*)d_in[0];
    const float4* pboxes  = (const float4*)d_in[1];
    const int*    tlabels = (const int*)d_in[2];
    const float4* tboxes  = (const float4*)d_in[3];
    float* out  = (float*)d_out;
    float* Cmat = out;                                   // [B,Q,T] float
    float* rows = out + (size_t)BB * QQ * TT;            // [B,T] as float
    float* cols = rows + (size_t)BB * TT;                // [B,T] as float
    cost_kernel<<<(BB * QQ) / 4, 256, 0, stream>>>(logits, pboxes, tlabels, tboxes, Cmat);
    lsa_kernel<<<BB, 64, 0, stream>>>(Cmat, rows, cols);
}